// Round 1
// baseline (1026.731 us; speedup 1.0000x reference)
//
#include <hip/hip_runtime.h>

typedef __bf16 bf16x8 __attribute__((ext_vector_type(8)));
typedef float f32x4 __attribute__((ext_vector_type(4)));
typedef unsigned short u16x8 __attribute__((ext_vector_type(8)));
typedef unsigned short u16x4 __attribute__((ext_vector_type(4)));

__device__ __forceinline__ unsigned short f2b(float f) {
    union { float f; unsigned int u; } v; v.f = f;
    unsigned int r = v.u + 0x7fffu + ((v.u >> 16) & 1u);
    return (unsigned short)(r >> 16);
}
__device__ __forceinline__ float b2f(unsigned short b) {
    union { unsigned int u; float f; } v; v.u = ((unsigned int)b) << 16;
    return v.f;
}

// ---------------- weight transpose + bf16 convert: W[K][NN] -> Wt[NN][K] ----------------
__global__ __launch_bounds__(256) void transpose_to_bf16(
    const float* __restrict__ W, unsigned short* __restrict__ Wt, int K, int NN)
{
    __shared__ float tile[32][33];
    int k0 = blockIdx.x * 32, n0 = blockIdx.y * 32;
    int tx = threadIdx.x & 31, ty = threadIdx.x >> 5;
    for (int r = ty; r < 32; r += 8)
        tile[r][tx] = W[(size_t)(k0 + r) * NN + n0 + tx];
    __syncthreads();
    for (int r = ty; r < 32; r += 8)
        Wt[(size_t)(n0 + r) * K + k0 + tx] = f2b(tile[tx][r]);
}

// ---------------- pe = x + pos_emb[positions] -> bf16 ----------------
__global__ __launch_bounds__(256) void add_posemb(
    const float* __restrict__ x, const int* __restrict__ pos,
    const float* __restrict__ pe, unsigned short* __restrict__ cur)
{
    size_t row = blockIdx.x;
    int t = threadIdx.x;
    int p = pos[row];
    float v = x[row * 256 + t] + pe[(size_t)p * 256 + t];
    cur[row * 256 + t] = f2b(v);
}

__global__ __launch_bounds__(256) void to_bf16_kernel(
    const float* __restrict__ in, unsigned short* __restrict__ o, int n)
{
    int i = blockIdx.x * 256 + threadIdx.x;
    int stride = gridDim.x * 256;
    for (; i < n; i += stride) o[i] = f2b(in[i]);
}

// ---------------- per-head-dim K/V/Q projections ----------------
// out[t, h*32+j] = sum_d in[t, h*32+d] * W[d][j]; qh additionally scaled by 1/16
__global__ __launch_bounds__(256) void proj_kvq(
    const unsigned short* __restrict__ cur, const unsigned short* __restrict__ qb,
    const float* __restrict__ Wq, const float* __restrict__ Wk, const float* __restrict__ Wv,
    unsigned short* __restrict__ qh, unsigned short* __restrict__ kk, unsigned short* __restrict__ vv)
{
    __shared__ float xc[8][256], xq[8][256];
    __shared__ float wq[32][33], wk[32][33], wv[32][33];
    int t = threadIdx.x;
    size_t row0 = (size_t)blockIdx.x * 8;
    for (int r = 0; r < 8; r++) {
        xc[r][t] = b2f(cur[(row0 + r) * 256 + t]);
        xq[r][t] = b2f(qb[(row0 + r) * 256 + t]);
    }
    #pragma unroll
    for (int i = 0; i < 4; i++) {
        int idx = t + i * 256, d = idx >> 5, j = idx & 31;
        wq[d][j] = Wq[idx]; wk[d][j] = Wk[idx]; wv[d][j] = Wv[idx];
    }
    __syncthreads();
    int h = t >> 5, j = t & 31;
    for (int r = 0; r < 8; r++) {
        float sq = 0.f, sk = 0.f, sv = 0.f;
        #pragma unroll
        for (int d = 0; d < 32; d++) {
            float xcv = xc[r][h * 32 + d], xqv = xq[r][h * 32 + d];
            sk = fmaf(xcv, wk[d][j], sk);
            sv = fmaf(xcv, wv[d][j], sv);
            sq = fmaf(xqv, wq[d][j], sq);
        }
        size_t o = (row0 + r) * 256 + t;
        qh[o] = f2b(sq * 0.0625f);   // fold 1/sqrt(E)=1/16 into qh
        kk[o] = f2b(sk);
        vv[o] = f2b(sv);
    }
}

// ---------------- fused attention per (n,h): S=Q=90, D=32 ----------------
__global__ __launch_bounds__(384) void attn_kernel(
    const unsigned short* __restrict__ qh, const unsigned short* __restrict__ kkg,
    const unsigned short* __restrict__ vvg, unsigned short* __restrict__ og)
{
    __shared__ __align__(16) unsigned short qs[96][40];
    __shared__ __align__(16) unsigned short ks[96][40];
    __shared__ __align__(16) unsigned short vt[32][104];
    __shared__ float sc[96][100];
    __shared__ __align__(16) unsigned short ps[96][104];

    int nh = blockIdx.x;
    int n = nh >> 3, h = nh & 7;
    int tid = threadIdx.x;
    int wave = tid >> 6, lane = tid & 63;

    // stage qh/k/v tiles (rows>=90 zero-padded); v stored transposed
    {
        int r = tid >> 2, s = tid & 3;
        u16x8 qv = {0,0,0,0,0,0,0,0}, kv = {0,0,0,0,0,0,0,0}, vv = {0,0,0,0,0,0,0,0};
        if (r < 90) {
            size_t base = ((size_t)(n * 90 + r)) * 256 + h * 32 + s * 8;
            qv = *(const u16x8*)&qh[base];
            kv = *(const u16x8*)&kkg[base];
            vv = *(const u16x8*)&vvg[base];
        }
        *(u16x8*)&qs[r][s * 8] = qv;
        *(u16x8*)&ks[r][s * 8] = kv;
        #pragma unroll
        for (int e = 0; e < 8; e++) vt[s * 8 + e][r] = vv[e];
    }
    __syncthreads();

    // scores: wave w computes 16-row m-tile w over 6 col tiles, K=32 (one MFMA)
    {
        int lr = lane & 15, lk = (lane >> 4) * 8, lg = lane >> 4;
        bf16x8 aq = *(const bf16x8*)&qs[wave * 16 + lr][lk];
        #pragma unroll
        for (int j = 0; j < 6; j++) {
            bf16x8 bk = *(const bf16x8*)&ks[j * 16 + lr][lk];
            f32x4 c = {0.f, 0.f, 0.f, 0.f};
            c = __builtin_amdgcn_mfma_f32_16x16x32_bf16(aq, bk, c, 0, 0, 0);
            #pragma unroll
            for (int rr = 0; rr < 4; rr++)
                sc[wave * 16 + lg * 4 + rr][j * 16 + lr] = c[rr];
        }
    }
    __syncthreads();

    // softmax: 4 threads per row over 90 cols; rows>=90 / cols>=90 -> P=0
    {
        int row = tid >> 2, q4 = tid & 3;
        float mx = -1e30f;
        for (int c = q4; c < 90; c += 4) mx = fmaxf(mx, sc[row][c]);
        mx = fmaxf(mx, __shfl_xor(mx, 1));
        mx = fmaxf(mx, __shfl_xor(mx, 2));
        float sum = 0.f;
        for (int c = q4; c < 90; c += 4) {
            float e = __expf(sc[row][c] - mx);
            sum += e;
            sc[row][c] = e;
        }
        sum += __shfl_xor(sum, 1);
        sum += __shfl_xor(sum, 2);
        float inv = 1.f / sum;
        for (int c = q4; c < 96; c += 4) {
            float pv = (c < 90 && row < 90) ? sc[row][c] * inv : 0.f;
            ps[row][c] = f2b(pv);
        }
    }
    __syncthreads();

    // PV: o[96][32]; wave w does m-tile w; K=96 -> 3 steps; 2 col tiles
    {
        int lr = lane & 15, lg = lane >> 4;
        f32x4 oc0 = {0.f,0.f,0.f,0.f}, oc1 = {0.f,0.f,0.f,0.f};
        #pragma unroll
        for (int s = 0; s < 3; s++) {
            int k0 = s * 32 + lg * 8;
            bf16x8 ap = *(const bf16x8*)&ps[wave * 16 + lr][k0];
            bf16x8 bv0 = *(const bf16x8*)&vt[0 + lr][k0];
            bf16x8 bv1 = *(const bf16x8*)&vt[16 + lr][k0];
            oc0 = __builtin_amdgcn_mfma_f32_16x16x32_bf16(ap, bv0, oc0, 0, 0, 0);
            oc1 = __builtin_amdgcn_mfma_f32_16x16x32_bf16(ap, bv1, oc1, 0, 0, 0);
        }
        #pragma unroll
        for (int rr = 0; rr < 4; rr++) {
            int row = wave * 16 + lg * 4 + rr;
            if (row < 90) {
                size_t base = ((size_t)(n * 90 + row)) * 256 + h * 32;
                og[base + lr]      = f2b(oc0[rr]);
                og[base + 16 + lr] = f2b(oc1[rr]);
            }
        }
    }
}

// ---------------- generic bf16 GEMM: C[M,NN] = A[M,K] * Bt[NN,K]^T + bias (+relu) ----------------
template<int RELU>
__global__ __launch_bounds__(256) void gemm_bf16(
    const unsigned short* __restrict__ A, const unsigned short* __restrict__ Bt,
    const float* __restrict__ bias, unsigned short* __restrict__ C,
    int M, int NN, int K)
{
    __shared__ __align__(16) unsigned short As[128][40];
    __shared__ __align__(16) unsigned short Bs[128][40];
    int tid = threadIdx.x;
    int wave = tid >> 6, lane = tid & 63;
    int wm = (wave >> 1) * 64, wn = (wave & 1) * 64;
    int row_a0 = blockIdx.x * 128, col_b0 = blockIdx.y * 128;
    int lr = lane & 15, lg = lane >> 4, lk = lg * 8;

    f32x4 acc[4][4];
    #pragma unroll
    for (int i = 0; i < 4; i++)
        #pragma unroll
        for (int j = 0; j < 4; j++)
            acc[i][j] = (f32x4){0.f, 0.f, 0.f, 0.f};

    for (int k0 = 0; k0 < K; k0 += 32) {
        __syncthreads();
        #pragma unroll
        for (int i = 0; i < 2; i++) {
            int c = tid + i * 256;
            int r = c >> 2, s = c & 3;
            *(u16x8*)&As[r][s * 8] = *(const u16x8*)&A[(size_t)(row_a0 + r) * K + k0 + s * 8];
            *(u16x8*)&Bs[r][s * 8] = *(const u16x8*)&Bt[(size_t)(col_b0 + r) * K + k0 + s * 8];
        }
        __syncthreads();
        bf16x8 af[4], bf[4];
        #pragma unroll
        for (int i = 0; i < 4; i++) af[i] = *(const bf16x8*)&As[wm + i * 16 + lr][lk];
        #pragma unroll
        for (int j = 0; j < 4; j++) bf[j] = *(const bf16x8*)&Bs[wn + j * 16 + lr][lk];
        #pragma unroll
        for (int i = 0; i < 4; i++)
            #pragma unroll
            for (int j = 0; j < 4; j++)
                acc[i][j] = __builtin_amdgcn_mfma_f32_16x16x32_bf16(af[i], bf[j], acc[i][j], 0, 0, 0);
    }

    #pragma unroll
    for (int j = 0; j < 4; j++) {
        int col = col_b0 + wn + j * 16 + lr;
        float bv = bias[col];
        #pragma unroll
        for (int i = 0; i < 4; i++) {
            #pragma unroll
            for (int rr = 0; rr < 4; rr++) {
                int row = row_a0 + wm + i * 16 + lg * 4 + rr;
                float v = acc[i][j][rr] + bv;
                if (RELU) v = fmaxf(v, 0.f);
                C[(size_t)row * NN + col] = f2b(v);
            }
        }
    }
}

// ---------------- residual + LayerNorm: out = LN(a + r) * g + b, bf16 out ----------------
__global__ __launch_bounds__(256) void ln_res(
    const unsigned short* __restrict__ a, const unsigned short* __restrict__ r,
    const float* __restrict__ g, const float* __restrict__ b,
    unsigned short* __restrict__ o)
{
    int wave = threadIdx.x >> 6, lane = threadIdx.x & 63;
    size_t row = (size_t)blockIdx.x * 4 + wave;
    size_t base = row * 256 + lane * 4;
    u16x4 av = *(const u16x4*)&a[base];
    u16x4 rv = *(const u16x4*)&r[base];
    float x[4];
    float s = 0.f, s2 = 0.f;
    #pragma unroll
    for (int i = 0; i < 4; i++) {
        x[i] = b2f(av[i]) + b2f(rv[i]);
        s += x[i];
        s2 += x[i] * x[i];
    }
    #pragma unroll
    for (int d = 1; d < 64; d <<= 1) {
        s += __shfl_xor(s, d);
        s2 += __shfl_xor(s2, d);
    }
    float m = s * (1.f / 256.f);
    float var = s2 * (1.f / 256.f) - m * m;
    float inv = rsqrtf(var + 1e-5f);
    u16x4 ov;
    #pragma unroll
    for (int i = 0; i < 4; i++) {
        int c = lane * 4 + i;
        ov[i] = f2b((x[i] - m) * inv * g[c] + b[c]);
    }
    *(u16x4*)&o[base] = ov;
}

// ---------------- classifier head: 256 -> 8 tanh -> 8 tanh -> 2 sigmoid ----------------
__global__ __launch_bounds__(256) void classifier(
    const unsigned short* __restrict__ xin,
    const float* __restrict__ Wc1, const float* __restrict__ bc1,
    const float* __restrict__ Wc2, const float* __restrict__ bc2,
    const float* __restrict__ Wc3, const float* __restrict__ bc3,
    float* __restrict__ out)
{
    __shared__ float w1[256][9];
    __shared__ float w2[64], b2s[8], w3[16], b3s[2], b1s[8];
    int t = threadIdx.x;
    #pragma unroll
    for (int i = 0; i < 8; i++) {
        int idx = t + i * 256;
        w1[idx >> 3][idx & 7] = Wc1[idx];
    }
    if (t < 64) w2[t] = Wc2[t];
    if (t < 16) w3[t] = Wc3[t];
    if (t < 8) { b2s[t] = bc2[t]; b1s[t] = bc1[t]; }
    if (t < 2) b3s[t] = bc3[t];
    __syncthreads();
    int g = t >> 3, m = t & 7;
    size_t row = (size_t)blockIdx.x * 32 + g;
    float z[8] = {0.f,0.f,0.f,0.f,0.f,0.f,0.f,0.f};
    const unsigned short* xr = xin + row * 256 + m * 32;
    #pragma unroll
    for (int c = 0; c < 4; c++) {
        u16x8 xv = *(const u16x8*)&xr[c * 8];
        #pragma unroll
        for (int e = 0; e < 8; e++) {
            float xf = b2f(xv[e]);
            int ei = m * 32 + c * 8 + e;
            #pragma unroll
            for (int j = 0; j < 8; j++) z[j] = fmaf(xf, w1[ei][j], z[j]);
        }
    }
    #pragma unroll
    for (int d = 1; d < 8; d <<= 1)
        #pragma unroll
        for (int j = 0; j < 8; j++) z[j] += __shfl_xor(z[j], d);
    float z1[8], z2[8];
    #pragma unroll
    for (int j = 0; j < 8; j++) z1[j] = tanhf(z[j] + b1s[j]);
    #pragma unroll
    for (int j2 = 0; j2 < 8; j2++) {
        float sacc = b2s[j2];
        #pragma unroll
        for (int j = 0; j < 8; j++) sacc = fmaf(z1[j], w2[j * 8 + j2], sacc);
        z2[j2] = tanhf(sacc);
    }
    if (m < 2) {
        float sacc = b3s[m];
        #pragma unroll
        for (int j = 0; j < 8; j++) sacc = fmaf(z2[j], w3[j * 2 + m], sacc);
        out[row * 2 + m] = 1.f / (1.f + __expf(-sacc));
    }
}

extern "C" void kernel_launch(void* const* d_in, const int* in_sizes, int n_in,
                              void* d_out, int out_size, void* d_ws, size_t ws_size,
                              hipStream_t stream) {
    const float* x        = (const float*)d_in[0];
    const float* q        = (const float*)d_in[1];
    const int*   positions= (const int*)d_in[2];
    const float* pos_emb  = (const float*)d_in[3];
    const float* Wq       = (const float*)d_in[4];
    const float* Wk       = (const float*)d_in[5];
    const float* Wv       = (const float*)d_in[6];
    const float* Wo       = (const float*)d_in[7];
    const float* bo       = (const float*)d_in[8];
    const float* g1       = (const float*)d_in[9];
    const float* b1       = (const float*)d_in[10];
    const float* g2       = (const float*)d_in[11];
    const float* b2       = (const float*)d_in[12];
    const float* Wf1      = (const float*)d_in[13];
    const float* bf1      = (const float*)d_in[14];
    const float* Wf2      = (const float*)d_in[15];
    const float* bf2      = (const float*)d_in[16];
    const float* Wc1      = (const float*)d_in[17];
    const float* bc1      = (const float*)d_in[18];
    const float* Wc2      = (const float*)d_in[19];
    const float* bc2      = (const float*)d_in[20];
    const float* Wc3      = (const float*)d_in[21];
    const float* bc3      = (const float*)d_in[22];
    float* out = (float*)d_out;

    const int R = 512 * 90;          // 46080 token rows
    char* ws = (char*)d_ws;
    size_t off = 0;
    auto alloc = [&](size_t bytes) -> void* {
        void* p = ws + off;
        off += (bytes + 255) & ~(size_t)255;
        return p;
    };
    unsigned short* cur = (unsigned short*)alloc((size_t)R * 256 * 2);
    unsigned short* qb  = (unsigned short*)alloc((size_t)R * 256 * 2);
    unsigned short* qho = (unsigned short*)alloc((size_t)R * 256 * 2);  // qh -> o -> h
    unsigned short* ka  = (unsigned short*)alloc((size_t)R * 256 * 2);  // k -> a
    unsigned short* vf  = (unsigned short*)alloc((size_t)R * 256 * 2);  // v -> f2
    unsigned short* f1  = (unsigned short*)alloc((size_t)R * 1024 * 2);
    unsigned short* WoT = (unsigned short*)alloc((size_t)3 * 256 * 256 * 2);
    unsigned short* W1T = (unsigned short*)alloc((size_t)3 * 1024 * 256 * 2);
    unsigned short* W2T = (unsigned short*)alloc((size_t)3 * 256 * 1024 * 2);

    for (int l = 0; l < 3; l++) {
        transpose_to_bf16<<<dim3(8, 8),  256, 0, stream>>>(Wo  + (size_t)l*256*256,  WoT + (size_t)l*256*256,  256, 256);
        transpose_to_bf16<<<dim3(8, 32), 256, 0, stream>>>(Wf1 + (size_t)l*256*1024, W1T + (size_t)l*1024*256, 256, 1024);
        transpose_to_bf16<<<dim3(32, 8), 256, 0, stream>>>(Wf2 + (size_t)l*1024*256, W2T + (size_t)l*256*1024, 1024, 256);
    }
    add_posemb<<<R, 256, 0, stream>>>(x, positions, pos_emb, cur);
    to_bf16_kernel<<<2048, 256, 0, stream>>>(q, qb, R * 256);

    for (int l = 0; l < 3; l++) {
        proj_kvq<<<R / 8, 256, 0, stream>>>(cur, qb,
            Wq + (size_t)l*1024, Wk + (size_t)l*1024, Wv + (size_t)l*1024,
            qho, ka, vf);
        attn_kernel<<<512 * 8, 384, 0, stream>>>(qho, ka, vf, qho);
        gemm_bf16<0><<<dim3(R / 128, 2), 256, 0, stream>>>(qho, WoT + (size_t)l*256*256, bo + l*256, ka, R, 256, 256);
        ln_res<<<R / 4, 256, 0, stream>>>(ka, qb, g1 + l*256, b1 + l*256, qho);
        gemm_bf16<1><<<dim3(R / 128, 8), 256, 0, stream>>>(qho, W1T + (size_t)l*1024*256, bf1 + l*1024, f1, R, 1024, 256);
        gemm_bf16<0><<<dim3(R / 128, 2), 256, 0, stream>>>(f1, W2T + (size_t)l*256*1024, bf2 + l*256, vf, R, 256, 1024);
        ln_res<<<R / 4, 256, 0, stream>>>(vf, qho, g2 + l*256, b2 + l*256, cur);
    }
    classifier<<<R / 32, 256, 0, stream>>>(cur, Wc1, bc1, Wc2, bc2, Wc3, bc3, out);
}

// Round 2
// 827.659 us; speedup vs baseline: 1.2405x; 1.2405x over previous
//
#include <hip/hip_runtime.h>

typedef __bf16 bf16x8 __attribute__((ext_vector_type(8)));
typedef __bf16 bf16x4 __attribute__((ext_vector_type(4)));
typedef float f32x4 __attribute__((ext_vector_type(4)));
typedef unsigned short u16x8 __attribute__((ext_vector_type(8)));
typedef unsigned short u16x4 __attribute__((ext_vector_type(4)));

__device__ __forceinline__ unsigned short f2b(float f) {
    union { float f; unsigned int u; } v; v.f = f;
    unsigned int r = v.u + 0x7fffu + ((v.u >> 16) & 1u);
    return (unsigned short)(r >> 16);
}
__device__ __forceinline__ float b2f(unsigned short b) {
    union { unsigned int u; float f; } v; v.u = ((unsigned int)b) << 16;
    return v.f;
}

__device__ __forceinline__ void gll16(const unsigned short* g, unsigned short* l) {
    __builtin_amdgcn_global_load_lds(
        (const __attribute__((address_space(1))) unsigned int*)g,
        (__attribute__((address_space(3))) unsigned int*)l, 16, 0, 0);
}

// ---------------- weight transpose + bf16 convert: W[K][NN] -> Wt[NN][K] ----------------
__global__ __launch_bounds__(256) void transpose_to_bf16(
    const float* __restrict__ W, unsigned short* __restrict__ Wt, int K, int NN)
{
    __shared__ float tile[32][33];
    int k0 = blockIdx.x * 32, n0 = blockIdx.y * 32;
    int tx = threadIdx.x & 31, ty = threadIdx.x >> 5;
    for (int r = ty; r < 32; r += 8)
        tile[r][tx] = W[(size_t)(k0 + r) * NN + n0 + tx];
    __syncthreads();
    for (int r = ty; r < 32; r += 8)
        Wt[(size_t)(n0 + r) * K + k0 + tx] = f2b(tile[tx][r]);
}

// ---------------- pe = x + pos_emb[positions] -> bf16 ----------------
__global__ __launch_bounds__(256) void add_posemb(
    const float* __restrict__ x, const int* __restrict__ pos,
    const float* __restrict__ pe, unsigned short* __restrict__ cur)
{
    size_t row = blockIdx.x;
    int t = threadIdx.x;
    int p = pos[row];
    float v = x[row * 256 + t] + pe[(size_t)p * 256 + t];
    cur[row * 256 + t] = f2b(v);
}

__global__ __launch_bounds__(256) void to_bf16_kernel(
    const float* __restrict__ in, unsigned short* __restrict__ o, int n)
{
    int i = blockIdx.x * 256 + threadIdx.x;
    int stride = gridDim.x * 256;
    for (; i < n; i += stride) o[i] = f2b(in[i]);
}

// ---------------- per-head-dim K/V/Q projections ----------------
__global__ __launch_bounds__(256) void proj_kvq(
    const unsigned short* __restrict__ cur, const unsigned short* __restrict__ qb,
    const float* __restrict__ Wq, const float* __restrict__ Wk, const float* __restrict__ Wv,
    unsigned short* __restrict__ qh, unsigned short* __restrict__ kk, unsigned short* __restrict__ vv)
{
    __shared__ float xc[8][256], xq[8][256];
    __shared__ float wq[32][33], wk[32][33], wv[32][33];
    int t = threadIdx.x;
    size_t row0 = (size_t)blockIdx.x * 8;
    for (int r = 0; r < 8; r++) {
        xc[r][t] = b2f(cur[(row0 + r) * 256 + t]);
        xq[r][t] = b2f(qb[(row0 + r) * 256 + t]);
    }
    #pragma unroll
    for (int i = 0; i < 4; i++) {
        int idx = t + i * 256, d = idx >> 5, j = idx & 31;
        wq[d][j] = Wq[idx]; wk[d][j] = Wk[idx]; wv[d][j] = Wv[idx];
    }
    __syncthreads();
    int h = t >> 5, j = t & 31;
    for (int r = 0; r < 8; r++) {
        float sq = 0.f, sk = 0.f, sv = 0.f;
        #pragma unroll
        for (int d = 0; d < 32; d++) {
            float xcv = xc[r][h * 32 + d], xqv = xq[r][h * 32 + d];
            sk = fmaf(xcv, wk[d][j], sk);
            sv = fmaf(xcv, wv[d][j], sv);
            sq = fmaf(xqv, wq[d][j], sq);
        }
        size_t o = (row0 + r) * 256 + t;
        qh[o] = f2b(sq * 0.0625f);   // fold 1/sqrt(E)=1/16 into qh
        kk[o] = f2b(sk);
        vv[o] = f2b(sv);
    }
}

// ---------------- fused attention per (n,h): S=Q=90, D=32 ----------------
// LDS regions: [qs[96][40] | ks[96][40]] overlaid by ps[96][104]; vs = subtiled V
__global__ __launch_bounds__(384, 8) void attn_kernel(
    const unsigned short* __restrict__ qh, const unsigned short* __restrict__ kkg,
    const unsigned short* __restrict__ vvg, unsigned short* __restrict__ og)
{
    __shared__ __align__(16) unsigned short smem[96 * 104 + 96 * 32];
    unsigned short* qs = smem;             // [96][40]
    unsigned short* ks = smem + 96 * 40;   // [96][40]
    unsigned short* ps = smem;             // [96][104]  (valid after barrier 2)
    unsigned short* vs = smem + 96 * 104;  // V subtiled: elem (k>>2)*128+(d>>4)*64+(k&3)*16+(d&15)

    int nh = blockIdx.x;
    int n = nh >> 3, h = nh & 7;
    int tid = threadIdx.x;
    int wave = tid >> 6, lane = tid & 63;
    int lr = lane & 15, lg = lane >> 4;

    // ---- stage q/k (padded rows) and V (subtiled) ----
    {
        int r = tid >> 2, s = tid & 3;
        u16x8 qv = {0,0,0,0,0,0,0,0}, kv = {0,0,0,0,0,0,0,0}, vvv = {0,0,0,0,0,0,0,0};
        if (r < 90) {
            size_t base = ((size_t)(n * 90 + r)) * 256 + h * 32 + s * 8;
            qv = *(const u16x8*)&qh[base];
            kv = *(const u16x8*)&kkg[base];
            vvv = *(const u16x8*)&vvg[base];
        }
        *(u16x8*)&qs[r * 40 + s * 8] = qv;
        *(u16x8*)&ks[r * 40 + s * 8] = kv;
        *(u16x8*)&vs[(r >> 2) * 128 + (s >> 1) * 64 + (r & 3) * 16 + (s & 1) * 8] = vvv;
    }
    __syncthreads();

    // ---- scores: wave w -> 16 q-rows x 96 k, K=32 (6 MFMAs), kept in registers ----
    f32x4 c[6];
    {
        bf16x8 aq = *(const bf16x8*)&qs[(wave * 16 + lr) * 40 + lg * 8];
        #pragma unroll
        for (int j = 0; j < 6; j++) {
            bf16x8 bk = *(const bf16x8*)&ks[(j * 16 + lr) * 40 + lg * 8];
            f32x4 z = {0.f, 0.f, 0.f, 0.f};
            c[j] = __builtin_amdgcn_mfma_f32_16x16x32_bf16(aq, bk, z, 0, 0, 0);
        }
    }
    if (lr >= 10) { c[5][0] = -1e30f; c[5][1] = -1e30f; c[5][2] = -1e30f; c[5][3] = -1e30f; }

    // ---- in-register softmax: rows = lg*4+rr, cols spread over j (in-reg) x lr (shfl 1/2/4/8) ----
    #pragma unroll
    for (int rr = 0; rr < 4; rr++) {
        float m = c[0][rr];
        #pragma unroll
        for (int j = 1; j < 6; j++) m = fmaxf(m, c[j][rr]);
        m = fmaxf(m, __shfl_xor(m, 1));
        m = fmaxf(m, __shfl_xor(m, 2));
        m = fmaxf(m, __shfl_xor(m, 4));
        m = fmaxf(m, __shfl_xor(m, 8));
        float sum = 0.f;
        #pragma unroll
        for (int j = 0; j < 6; j++) {
            float e = __expf(c[j][rr] - m);
            c[j][rr] = e;
            sum += e;
        }
        sum += __shfl_xor(sum, 1);
        sum += __shfl_xor(sum, 2);
        sum += __shfl_xor(sum, 4);
        sum += __shfl_xor(sum, 8);
        float inv = 1.f / sum;
        #pragma unroll
        for (int j = 0; j < 6; j++) c[j][rr] *= inv;
    }
    __syncthreads();   // qs/ks now dead; ps may overlay

    // ---- write P as bf16, paired u32 (even lanes rr 0/1, odd lanes rr 2/3) ----
    {
        int row_base = wave * 16 + lg * 4;
        int hiw = lane & 1;
        #pragma unroll
        for (int j = 0; j < 6; j++) {
            #pragma unroll
            for (int rr = 0; rr < 4; rr++) {
                float oth = __shfl_xor(c[j][rr], 1);
                unsigned int own16 = f2b(c[j][rr]), oth16 = f2b(oth);
                unsigned int pk = hiw ? (oth16 | (own16 << 16)) : (own16 | (oth16 << 16));
                if ((rr >> 1) == hiw)
                    *(unsigned int*)&ps[(row_base + rr) * 104 + j * 16 + (lr & ~1)] = pk;
            }
        }
    }
    __syncthreads();

    // ---- PV: A from ps rows; B via ds_read_b64_tr_b16 from subtiled V ----
    {
        unsigned vbase = (unsigned)(size_t)&vs[0];
        f32x4 oc0 = {0.f,0.f,0.f,0.f}, oc1 = {0.f,0.f,0.f,0.f};
        #pragma unroll
        for (int s = 0; s < 3; s++) {
            bf16x8 ap = *(const bf16x8*)&ps[(wave * 16 + lr) * 104 + s * 32 + lg * 8];
            unsigned ta = vbase + (unsigned)((8 * s + 2 * lg) * 256) + (unsigned)(lr * 8);
            bf16x4 b0a, b0b, b1a, b1b;
            asm volatile(
                "ds_read_b64_tr_b16 %0, %4\n\t"
                "ds_read_b64_tr_b16 %1, %4 offset:256\n\t"
                "ds_read_b64_tr_b16 %2, %4 offset:128\n\t"
                "ds_read_b64_tr_b16 %3, %4 offset:384\n\t"
                "s_waitcnt lgkmcnt(0)"
                : "=&v"(b0a), "=&v"(b0b), "=&v"(b1a), "=&v"(b1b)
                : "v"(ta) : "memory");
            __builtin_amdgcn_sched_barrier(0);
            bf16x8 bv0, bv1;
            #pragma unroll
            for (int e = 0; e < 4; e++) {
                bv0[e] = b0a[e]; bv0[4 + e] = b0b[e];
                bv1[e] = b1a[e]; bv1[4 + e] = b1b[e];
            }
            oc0 = __builtin_amdgcn_mfma_f32_16x16x32_bf16(ap, bv0, oc0, 0, 0, 0);
            oc1 = __builtin_amdgcn_mfma_f32_16x16x32_bf16(ap, bv1, oc1, 0, 0, 0);
        }
        #pragma unroll
        for (int rr = 0; rr < 4; rr++) {
            int row = wave * 16 + lg * 4 + rr;
            if (row < 90) {
                size_t base = ((size_t)(n * 90 + row)) * 256 + h * 32;
                og[base + lr]      = f2b(oc0[rr]);
                og[base + 16 + lr] = f2b(oc1[rr]);
            }
        }
    }
}

// ---------------- generic bf16 GEMM: C[M,NN] = A[M,K] * Bt[NN,K]^T + bias (+relu) ----------------
// global_load_lds staging into unpadded [128][32] LDS; source-side XOR swizzle (chunk ^= row&3)
template<int RELU>
__global__ __launch_bounds__(256) void gemm_bf16(
    const unsigned short* __restrict__ A, const unsigned short* __restrict__ Bt,
    const float* __restrict__ bias, unsigned short* __restrict__ C,
    int M, int NN, int K)
{
    __shared__ __align__(16) unsigned short As[128 * 32];
    __shared__ __align__(16) unsigned short Bs[128 * 32];
    int tid = threadIdx.x;
    int wave = tid >> 6, lane = tid & 63;
    int wm = (wave >> 1) * 64, wn = (wave & 1) * 64;
    int row_a0 = blockIdx.x * 128, col_b0 = blockIdx.y * 128;
    int lr = lane & 15, lg = lane >> 4;
    int swz = (lg ^ (lr & 3)) * 8;

    f32x4 acc[4][4];
    #pragma unroll
    for (int i = 0; i < 4; i++)
        #pragma unroll
        for (int j = 0; j < 4; j++)
            acc[i][j] = (f32x4){0.f, 0.f, 0.f, 0.f};

    for (int k0 = 0; k0 < K; k0 += 32) {
        __syncthreads();
        #pragma unroll
        for (int i = 0; i < 2; i++) {
            int p = tid + i * 256;            // physical 16B chunk index
            int r = p >> 2, sp = p & 3;
            int sl = sp ^ (r & 3);            // logical k-chunk (source pre-swizzle)
            gll16(&A[(size_t)(row_a0 + r) * K + k0 + sl * 8], &As[(wave * 64 + i * 256) * 8]);
            gll16(&Bt[(size_t)(col_b0 + r) * K + k0 + sl * 8], &Bs[(wave * 64 + i * 256) * 8]);
        }
        __syncthreads();
        bf16x8 af[4], bfr[4];
        #pragma unroll
        for (int i = 0; i < 4; i++) af[i] = *(const bf16x8*)&As[(wm + i * 16 + lr) * 32 + swz];
        #pragma unroll
        for (int j = 0; j < 4; j++) bfr[j] = *(const bf16x8*)&Bs[(wn + j * 16 + lr) * 32 + swz];
        #pragma unroll
        for (int i = 0; i < 4; i++)
            #pragma unroll
            for (int j = 0; j < 4; j++)
                acc[i][j] = __builtin_amdgcn_mfma_f32_16x16x32_bf16(af[i], bfr[j], acc[i][j], 0, 0, 0);
    }

    #pragma unroll
    for (int j = 0; j < 4; j++) {
        int col = col_b0 + wn + j * 16 + lr;
        float bv = bias[col];
        #pragma unroll
        for (int i = 0; i < 4; i++) {
            #pragma unroll
            for (int rr = 0; rr < 4; rr++) {
                int row = row_a0 + wm + i * 16 + lg * 4 + rr;
                float v = acc[i][j][rr] + bv;
                if (RELU) v = fmaxf(v, 0.f);
                C[(size_t)row * NN + col] = f2b(v);
            }
        }
    }
}

// ---------------- residual + LayerNorm ----------------
__global__ __launch_bounds__(256) void ln_res(
    const unsigned short* __restrict__ a, const unsigned short* __restrict__ r,
    const float* __restrict__ g, const float* __restrict__ b,
    unsigned short* __restrict__ o)
{
    int wave = threadIdx.x >> 6, lane = threadIdx.x & 63;
    size_t row = (size_t)blockIdx.x * 4 + wave;
    size_t base = row * 256 + lane * 4;
    u16x4 av = *(const u16x4*)&a[base];
    u16x4 rv = *(const u16x4*)&r[base];
    float x[4];
    float s = 0.f, s2 = 0.f;
    #pragma unroll
    for (int i = 0; i < 4; i++) {
        x[i] = b2f(av[i]) + b2f(rv[i]);
        s += x[i];
        s2 += x[i] * x[i];
    }
    #pragma unroll
    for (int d = 1; d < 64; d <<= 1) {
        s += __shfl_xor(s, d);
        s2 += __shfl_xor(s2, d);
    }
    float m = s * (1.f / 256.f);
    float var = s2 * (1.f / 256.f) - m * m;
    float inv = rsqrtf(var + 1e-5f);
    u16x4 ov;
    #pragma unroll
    for (int i = 0; i < 4; i++) {
        int cc = lane * 4 + i;
        ov[i] = f2b((x[i] - m) * inv * g[cc] + b[cc]);
    }
    *(u16x4*)&o[base] = ov;
}

// ---------------- classifier head ----------------
__global__ __launch_bounds__(256) void classifier(
    const unsigned short* __restrict__ xin,
    const float* __restrict__ Wc1, const float* __restrict__ bc1,
    const float* __restrict__ Wc2, const float* __restrict__ bc2,
    const float* __restrict__ Wc3, const float* __restrict__ bc3,
    float* __restrict__ out)
{
    __shared__ float w1[256][9];
    __shared__ float w2[64], b2s[8], w3[16], b3s[2], b1s[8];
    int t = threadIdx.x;
    #pragma unroll
    for (int i = 0; i < 8; i++) {
        int idx = t + i * 256;
        w1[idx >> 3][idx & 7] = Wc1[idx];
    }
    if (t < 64) w2[t] = Wc2[t];
    if (t < 16) w3[t] = Wc3[t];
    if (t < 8) { b2s[t] = bc2[t]; b1s[t] = bc1[t]; }
    if (t < 2) b3s[t] = bc3[t];
    __syncthreads();
    int g = t >> 3, m = t & 7;
    size_t row = (size_t)blockIdx.x * 32 + g;
    float z[8] = {0.f,0.f,0.f,0.f,0.f,0.f,0.f,0.f};
    const unsigned short* xr = xin + row * 256 + m * 32;
    #pragma unroll
    for (int cidx = 0; cidx < 4; cidx++) {
        u16x8 xv = *(const u16x8*)&xr[cidx * 8];
        #pragma unroll
        for (int e = 0; e < 8; e++) {
            float xf = b2f(xv[e]);
            int ei = m * 32 + cidx * 8 + e;
            #pragma unroll
            for (int j = 0; j < 8; j++) z[j] = fmaf(xf, w1[ei][j], z[j]);
        }
    }
    #pragma unroll
    for (int d = 1; d < 8; d <<= 1)
        #pragma unroll
        for (int j = 0; j < 8; j++) z[j] += __shfl_xor(z[j], d);
    float z1[8], z2[8];
    #pragma unroll
    for (int j = 0; j < 8; j++) z1[j] = tanhf(z[j] + b1s[j]);
    #pragma unroll
    for (int j2 = 0; j2 < 8; j2++) {
        float sacc = b2s[j2];
        #pragma unroll
        for (int j = 0; j < 8; j++) sacc = fmaf(z1[j], w2[j * 8 + j2], sacc);
        z2[j2] = tanhf(sacc);
    }
    if (m < 2) {
        float sacc = b3s[m];
        #pragma unroll
        for (int j = 0; j < 8; j++) sacc = fmaf(z2[j], w3[j * 2 + m], sacc);
        out[row * 2 + m] = 1.f / (1.f + __expf(-sacc));
    }
}

extern "C" void kernel_launch(void* const* d_in, const int* in_sizes, int n_in,
                              void* d_out, int out_size, void* d_ws, size_t ws_size,
                              hipStream_t stream) {
    const float* x        = (const float*)d_in[0];
    const float* q        = (const float*)d_in[1];
    const int*   positions= (const int*)d_in[2];
    const float* pos_emb  = (const float*)d_in[3];
    const float* Wq       = (const float*)d_in[4];
    const float* Wk       = (const float*)d_in[5];
    const float* Wv       = (const float*)d_in[6];
    const float* Wo       = (const float*)d_in[7];
    const float* bo       = (const float*)d_in[8];
    const float* g1       = (const float*)d_in[9];
    const float* b1       = (const float*)d_in[10];
    const float* g2       = (const float*)d_in[11];
    const float* b2       = (const float*)d_in[12];
    const float* Wf1      = (const float*)d_in[13];
    const float* bf1      = (const float*)d_in[14];
    const float* Wf2      = (const float*)d_in[15];
    const float* bf2      = (const float*)d_in[16];
    const float* Wc1      = (const float*)d_in[17];
    const float* bc1      = (const float*)d_in[18];
    const float* Wc2      = (const float*)d_in[19];
    const float* bc2      = (const float*)d_in[20];
    const float* Wc3      = (const float*)d_in[21];
    const float* bc3      = (const float*)d_in[22];
    float* out = (float*)d_out;

    const int R = 512 * 90;          // 46080 token rows
    char* ws = (char*)d_ws;
    size_t off = 0;
    auto alloc = [&](size_t bytes) -> void* {
        void* p = ws + off;
        off += (bytes + 255) & ~(size_t)255;
        return p;
    };
    unsigned short* cur = (unsigned short*)alloc((size_t)R * 256 * 2);
    unsigned short* qb  = (unsigned short*)alloc((size_t)R * 256 * 2);
    unsigned short* qho = (unsigned short*)alloc((size_t)R * 256 * 2);  // qh -> o -> h
    unsigned short* ka  = (unsigned short*)alloc((size_t)R * 256 * 2);  // k -> a
    unsigned short* vf  = (unsigned short*)alloc((size_t)R * 256 * 2);  // v -> f2
    unsigned short* f1  = (unsigned short*)alloc((size_t)R * 1024 * 2);
    unsigned short* WoT = (unsigned short*)alloc((size_t)3 * 256 * 256 * 2);
    unsigned short* W1T = (unsigned short*)alloc((size_t)3 * 1024 * 256 * 2);
    unsigned short* W2T = (unsigned short*)alloc((size_t)3 * 256 * 1024 * 2);

    for (int l = 0; l < 3; l++) {
        transpose_to_bf16<<<dim3(8, 8),  256, 0, stream>>>(Wo  + (size_t)l*256*256,  WoT + (size_t)l*256*256,  256, 256);
        transpose_to_bf16<<<dim3(8, 32), 256, 0, stream>>>(Wf1 + (size_t)l*256*1024, W1T + (size_t)l*1024*256, 256, 1024);
        transpose_to_bf16<<<dim3(32, 8), 256, 0, stream>>>(Wf2 + (size_t)l*1024*256, W2T + (size_t)l*256*1024, 1024, 256);
    }
    add_posemb<<<R, 256, 0, stream>>>(x, positions, pos_emb, cur);
    to_bf16_kernel<<<2048, 256, 0, stream>>>(q, qb, R * 256);

    for (int l = 0; l < 3; l++) {
        proj_kvq<<<R / 8, 256, 0, stream>>>(cur, qb,
            Wq + (size_t)l*1024, Wk + (size_t)l*1024, Wv + (size_t)l*1024,
            qho, ka, vf);
        attn_kernel<<<512 * 8, 384, 0, stream>>>(qho, ka, vf, qho);
        gemm_bf16<0><<<dim3(R / 128, 2), 256, 0, stream>>>(qho, WoT + (size_t)l*256*256, bo + l*256, ka, R, 256, 256);
        ln_res<<<R / 4, 256, 0, stream>>>(ka, qb, g1 + l*256, b1 + l*256, qho);
        gemm_bf16<1><<<dim3(R / 128, 8), 256, 0, stream>>>(qho, W1T + (size_t)l*1024*256, bf1 + l*1024, f1, R, 1024, 256);
        gemm_bf16<0><<<dim3(R / 128, 2), 256, 0, stream>>>(f1, W2T + (size_t)l*256*1024, bf2 + l*256, vf, R, 256, 1024);
        ln_res<<<R / 4, 256, 0, stream>>>(vf, qho, g2 + l*256, b2 + l*256, cur);
    }
    classifier<<<R / 32, 256, 0, stream>>>(cur, Wc1, bc1, Wc2, bc2, Wc3, bc3, out);
}

// Round 3
// 669.882 us; speedup vs baseline: 1.5327x; 1.2355x over previous
//
#include <hip/hip_runtime.h>

typedef __bf16 bf16x8 __attribute__((ext_vector_type(8)));
typedef __bf16 bf16x4 __attribute__((ext_vector_type(4)));
typedef float f32x4 __attribute__((ext_vector_type(4)));
typedef unsigned short u16x8 __attribute__((ext_vector_type(8)));
typedef unsigned short u16x4 __attribute__((ext_vector_type(4)));

__device__ __forceinline__ unsigned short f2b(float f) {
    union { float f; unsigned int u; } v; v.f = f;
    unsigned int r = v.u + 0x7fffu + ((v.u >> 16) & 1u);
    return (unsigned short)(r >> 16);
}
__device__ __forceinline__ float b2f(unsigned short b) {
    union { unsigned int u; float f; } v; v.u = ((unsigned int)b) << 16;
    return v.f;
}

__device__ __forceinline__ void gll16(const unsigned short* g, unsigned short* l) {
    __builtin_amdgcn_global_load_lds(
        (const __attribute__((address_space(1))) unsigned int*)g,
        (__attribute__((address_space(3))) unsigned int*)l, 16, 0, 0);
}

// ---------------- weight transpose + bf16 convert: W[K][NN] -> Wt[NN][K] ----------------
__global__ __launch_bounds__(256) void transpose_to_bf16(
    const float* __restrict__ W, unsigned short* __restrict__ Wt, int K, int NN)
{
    __shared__ float tile[32][33];
    int k0 = blockIdx.x * 32, n0 = blockIdx.y * 32;
    int tx = threadIdx.x & 31, ty = threadIdx.x >> 5;
    for (int r = ty; r < 32; r += 8)
        tile[r][tx] = W[(size_t)(k0 + r) * NN + n0 + tx];
    __syncthreads();
    for (int r = ty; r < 32; r += 8)
        Wt[(size_t)(n0 + r) * K + k0 + tx] = f2b(tile[tx][r]);
}

// ---------------- per-layer Q/K/V weight transpose: W[32][32] f32 -> WT[j][d] bf16 ----------------
// grid = 9 blocks (3 layers x 3 matrices); Wq scaled by 1/16
__global__ __launch_bounds__(256) void prep_wT(
    const float* __restrict__ Wq, const float* __restrict__ Wk, const float* __restrict__ Wv,
    unsigned short* __restrict__ wT)
{
    int l = blockIdx.x / 3, w = blockIdx.x % 3;
    const float* src = (w == 0 ? Wq : w == 1 ? Wk : Wv) + (size_t)l * 1024;
    unsigned short* dst = wT + ((size_t)l * 3 + w) * 1024;
    float scale = (w == 0) ? 0.0625f : 1.0f;
    int t = threadIdx.x;
    f32x4 v = *(const f32x4*)&src[t * 4];
    int d = (t * 4) >> 5, j0 = (t * 4) & 31;
    #pragma unroll
    for (int e = 0; e < 4; e++)
        dst[(j0 + e) * 32 + d] = f2b(v[e] * scale);
}

// ---------------- pe = x + pos_emb[positions] -> bf16 ----------------
__global__ __launch_bounds__(256) void add_posemb(
    const float* __restrict__ x, const int* __restrict__ pos,
    const float* __restrict__ pe, unsigned short* __restrict__ cur)
{
    size_t row = blockIdx.x;
    int t = threadIdx.x;
    int p = pos[row];
    float v = x[row * 256 + t] + pe[(size_t)p * 256 + t];
    cur[row * 256 + t] = f2b(v);
}

__global__ __launch_bounds__(256) void to_bf16_kernel(
    const float* __restrict__ in, unsigned short* __restrict__ o, int n)
{
    int i = blockIdx.x * 256 + threadIdx.x;
    int stride = gridDim.x * 256;
    for (; i < n; i += stride) o[i] = f2b(in[i]);
}

// ---------------- fused attention per (n,h): projections + softmax(QK^T)V ----------------
// LDS: [qs[96][40] | ks[96][40]] overlaid by ps[96][104]; vs = subtiled V
__global__ __launch_bounds__(384, 2) void attn_kernel(
    const unsigned short* __restrict__ cur, const unsigned short* __restrict__ qb,
    const unsigned short* __restrict__ wT,   // this layer: [wq|wk|wv] each [32][32] bf16 (j-major)
    unsigned short* __restrict__ og)
{
    __shared__ __align__(16) unsigned short smem[96 * 104 + 96 * 32];
    unsigned short* qs = smem;             // [96][40]
    unsigned short* ks = smem + 96 * 40;   // [96][40]
    unsigned short* ps = smem;             // [96][104]  (valid after barrier 2)
    unsigned short* vs = smem + 96 * 104;  // V subtiled: elem (k>>2)*128+(d>>4)*64+(k&3)*16+(d&15)

    int nh = blockIdx.x;
    int n = nh >> 3, h = nh & 7;
    int tid = threadIdx.x;
    int wave = tid >> 6, lane = tid & 63;
    int lr = lane & 15, lg = lane >> 4;
    int hiw = lane & 1;

    // ---- W B-fragments (L2-resident, 2KB/matrix) ----
    bf16x8 wq[2], wk[2], wv[2];
    #pragma unroll
    for (int ct = 0; ct < 2; ct++) {
        int o = (ct * 16 + lr) * 32 + lg * 8;
        wq[ct] = *(const bf16x8*)&wT[o];
        wk[ct] = *(const bf16x8*)&wT[1024 + o];
        wv[ct] = *(const bf16x8*)&wT[2048 + o];
    }

    // ---- fused projection: wave w computes token rows w*16..w*16+15 ----
    {
        int tile = wave;
        int row = tile * 16 + lr;
        bf16x8 aq = {0,0,0,0,0,0,0,0}, ac = {0,0,0,0,0,0,0,0};
        if (row < 90) {
            size_t base = ((size_t)(n * 90 + row)) * 256 + h * 32 + lg * 8;
            aq = *(const bf16x8*)&qb[base];
            ac = *(const bf16x8*)&cur[base];
        }
        f32x4 zz = {0.f, 0.f, 0.f, 0.f};
        #pragma unroll
        for (int ct = 0; ct < 2; ct++) {
            f32x4 qc = __builtin_amdgcn_mfma_f32_16x16x32_bf16(aq, wq[ct], zz, 0, 0, 0);
            f32x4 kc = __builtin_amdgcn_mfma_f32_16x16x32_bf16(ac, wk[ct], zz, 0, 0, 0);
            f32x4 vc = __builtin_amdgcn_mfma_f32_16x16x32_bf16(ac, wv[ct], zz, 0, 0, 0);
            #pragma unroll
            for (int rr = 0; rr < 4; rr++) {
                // paired u32 writes: even lanes own rr 0/1, odd lanes rr 2/3
                float oq = __shfl_xor(qc[rr], 1);
                unsigned a16 = f2b(qc[rr]), o16 = f2b(oq);
                unsigned pk = hiw ? (o16 | (a16 << 16)) : (a16 | (o16 << 16));
                if ((rr >> 1) == hiw)
                    *(unsigned*)&qs[(tile * 16 + lg * 4 + rr) * 40 + ct * 16 + (lr & ~1)] = pk;

                float ok = __shfl_xor(kc[rr], 1);
                a16 = f2b(kc[rr]); o16 = f2b(ok);
                pk = hiw ? (o16 | (a16 << 16)) : (a16 | (o16 << 16));
                if ((rr >> 1) == hiw)
                    *(unsigned*)&ks[(tile * 16 + lg * 4 + rr) * 40 + ct * 16 + (lr & ~1)] = pk;

                float ov = __shfl_xor(vc[rr], 1);
                a16 = f2b(vc[rr]); o16 = f2b(ov);
                pk = hiw ? (o16 | (a16 << 16)) : (a16 | (o16 << 16));
                if ((rr >> 1) == hiw)
                    *(unsigned*)&vs[(tile * 4 + lg) * 128 + ct * 64 + rr * 16 + (lr & ~1)] = pk;
            }
        }
    }
    __syncthreads();

    // ---- scores: wave w -> 16 q-rows x 96 k, K=32 (6 MFMAs), kept in registers ----
    f32x4 c[6];
    {
        bf16x8 aq = *(const bf16x8*)&qs[(wave * 16 + lr) * 40 + lg * 8];
        #pragma unroll
        for (int j = 0; j < 6; j++) {
            bf16x8 bk = *(const bf16x8*)&ks[(j * 16 + lr) * 40 + lg * 8];
            f32x4 z = {0.f, 0.f, 0.f, 0.f};
            c[j] = __builtin_amdgcn_mfma_f32_16x16x32_bf16(aq, bk, z, 0, 0, 0);
        }
    }
    if (lr >= 10) { c[5][0] = -1e30f; c[5][1] = -1e30f; c[5][2] = -1e30f; c[5][3] = -1e30f; }

    // ---- in-register softmax ----
    #pragma unroll
    for (int rr = 0; rr < 4; rr++) {
        float m = c[0][rr];
        #pragma unroll
        for (int j = 1; j < 6; j++) m = fmaxf(m, c[j][rr]);
        m = fmaxf(m, __shfl_xor(m, 1));
        m = fmaxf(m, __shfl_xor(m, 2));
        m = fmaxf(m, __shfl_xor(m, 4));
        m = fmaxf(m, __shfl_xor(m, 8));
        float sum = 0.f;
        #pragma unroll
        for (int j = 0; j < 6; j++) {
            float e = __expf(c[j][rr] - m);
            c[j][rr] = e;
            sum += e;
        }
        sum += __shfl_xor(sum, 1);
        sum += __shfl_xor(sum, 2);
        sum += __shfl_xor(sum, 4);
        sum += __shfl_xor(sum, 8);
        float inv = 1.f / sum;
        #pragma unroll
        for (int j = 0; j < 6; j++) c[j][rr] *= inv;
    }
    __syncthreads();   // qs/ks now dead; ps may overlay

    // ---- write P as bf16, paired u32 ----
    {
        int row_base = wave * 16 + lg * 4;
        #pragma unroll
        for (int j = 0; j < 6; j++) {
            #pragma unroll
            for (int rr = 0; rr < 4; rr++) {
                float oth = __shfl_xor(c[j][rr], 1);
                unsigned int own16 = f2b(c[j][rr]), oth16 = f2b(oth);
                unsigned int pk = hiw ? (oth16 | (own16 << 16)) : (own16 | (oth16 << 16));
                if ((rr >> 1) == hiw)
                    *(unsigned int*)&ps[(row_base + rr) * 104 + j * 16 + (lr & ~1)] = pk;
            }
        }
    }
    __syncthreads();

    // ---- PV: A from ps rows; B via ds_read_b64_tr_b16 from subtiled V ----
    {
        unsigned vbase = (unsigned)(size_t)&vs[0];
        f32x4 oc0 = {0.f,0.f,0.f,0.f}, oc1 = {0.f,0.f,0.f,0.f};
        #pragma unroll
        for (int s = 0; s < 3; s++) {
            bf16x8 ap = *(const bf16x8*)&ps[(wave * 16 + lr) * 104 + s * 32 + lg * 8];
            unsigned ta = vbase + (unsigned)((8 * s + 2 * lg) * 256) + (unsigned)(lr * 8);
            bf16x4 b0a, b0b, b1a, b1b;
            asm volatile(
                "ds_read_b64_tr_b16 %0, %4\n\t"
                "ds_read_b64_tr_b16 %1, %4 offset:256\n\t"
                "ds_read_b64_tr_b16 %2, %4 offset:128\n\t"
                "ds_read_b64_tr_b16 %3, %4 offset:384\n\t"
                "s_waitcnt lgkmcnt(0)"
                : "=&v"(b0a), "=&v"(b0b), "=&v"(b1a), "=&v"(b1b)
                : "v"(ta) : "memory");
            __builtin_amdgcn_sched_barrier(0);
            bf16x8 bv0, bv1;
            #pragma unroll
            for (int e = 0; e < 4; e++) {
                bv0[e] = b0a[e]; bv0[4 + e] = b0b[e];
                bv1[e] = b1a[e]; bv1[4 + e] = b1b[e];
            }
            oc0 = __builtin_amdgcn_mfma_f32_16x16x32_bf16(ap, bv0, oc0, 0, 0, 0);
            oc1 = __builtin_amdgcn_mfma_f32_16x16x32_bf16(ap, bv1, oc1, 0, 0, 0);
        }
        #pragma unroll
        for (int rr = 0; rr < 4; rr++) {
            int row = wave * 16 + lg * 4 + rr;
            if (row < 90) {
                size_t base = ((size_t)(n * 90 + row)) * 256 + h * 32;
                og[base + lr]      = f2b(oc0[rr]);
                og[base + 16 + lr] = f2b(oc1[rr]);
            }
        }
    }
}

// ---------------- generic bf16 GEMM: C[M,NN] = A[M,K] * Bt[NN,K]^T + bias (+relu) ----------------
template<int RELU>
__global__ __launch_bounds__(256) void gemm_bf16(
    const unsigned short* __restrict__ A, const unsigned short* __restrict__ Bt,
    const float* __restrict__ bias, unsigned short* __restrict__ C,
    int M, int NN, int K)
{
    __shared__ __align__(16) unsigned short As[128 * 32];
    __shared__ __align__(16) unsigned short Bs[128 * 32];
    int tid = threadIdx.x;
    int wave = tid >> 6, lane = tid & 63;
    int wm = (wave >> 1) * 64, wn = (wave & 1) * 64;
    int row_a0 = blockIdx.x * 128, col_b0 = blockIdx.y * 128;
    int lr = lane & 15, lg = lane >> 4;
    int swz = (lg ^ (lr & 3)) * 8;

    f32x4 acc[4][4];
    #pragma unroll
    for (int i = 0; i < 4; i++)
        #pragma unroll
        for (int j = 0; j < 4; j++)
            acc[i][j] = (f32x4){0.f, 0.f, 0.f, 0.f};

    for (int k0 = 0; k0 < K; k0 += 32) {
        __syncthreads();
        #pragma unroll
        for (int i = 0; i < 2; i++) {
            int p = tid + i * 256;            // physical 16B chunk index
            int r = p >> 2, sp = p & 3;
            int sl = sp ^ (r & 3);            // logical k-chunk (source pre-swizzle)
            gll16(&A[(size_t)(row_a0 + r) * K + k0 + sl * 8], &As[(wave * 64 + i * 256) * 8]);
            gll16(&Bt[(size_t)(col_b0 + r) * K + k0 + sl * 8], &Bs[(wave * 64 + i * 256) * 8]);
        }
        __syncthreads();
        bf16x8 af[4], bfr[4];
        #pragma unroll
        for (int i = 0; i < 4; i++) af[i] = *(const bf16x8*)&As[(wm + i * 16 + lr) * 32 + swz];
        #pragma unroll
        for (int j = 0; j < 4; j++) bfr[j] = *(const bf16x8*)&Bs[(wn + j * 16 + lr) * 32 + swz];
        #pragma unroll
        for (int i = 0; i < 4; i++)
            #pragma unroll
            for (int j = 0; j < 4; j++)
                acc[i][j] = __builtin_amdgcn_mfma_f32_16x16x32_bf16(af[i], bfr[j], acc[i][j], 0, 0, 0);
    }

    #pragma unroll
    for (int j = 0; j < 4; j++) {
        int col = col_b0 + wn + j * 16 + lr;
        float bv = bias[col];
        #pragma unroll
        for (int i = 0; i < 4; i++) {
            #pragma unroll
            for (int rr = 0; rr < 4; rr++) {
                int row = row_a0 + wm + i * 16 + lg * 4 + rr;
                float v = acc[i][j][rr] + bv;
                if (RELU) v = fmaxf(v, 0.f);
                C[(size_t)row * NN + col] = f2b(v);
            }
        }
    }
}

// ---------------- residual + LayerNorm ----------------
__global__ __launch_bounds__(256) void ln_res(
    const unsigned short* __restrict__ a, const unsigned short* __restrict__ r,
    const float* __restrict__ g, const float* __restrict__ b,
    unsigned short* __restrict__ o)
{
    int wave = threadIdx.x >> 6, lane = threadIdx.x & 63;
    size_t row = (size_t)blockIdx.x * 4 + wave;
    size_t base = row * 256 + lane * 4;
    u16x4 av = *(const u16x4*)&a[base];
    u16x4 rv = *(const u16x4*)&r[base];
    float x[4];
    float s = 0.f, s2 = 0.f;
    #pragma unroll
    for (int i = 0; i < 4; i++) {
        x[i] = b2f(av[i]) + b2f(rv[i]);
        s += x[i];
        s2 += x[i] * x[i];
    }
    #pragma unroll
    for (int d = 1; d < 64; d <<= 1) {
        s += __shfl_xor(s, d);
        s2 += __shfl_xor(s2, d);
    }
    float m = s * (1.f / 256.f);
    float var = s2 * (1.f / 256.f) - m * m;
    float inv = rsqrtf(var + 1e-5f);
    u16x4 ov;
    #pragma unroll
    for (int i = 0; i < 4; i++) {
        int cc = lane * 4 + i;
        ov[i] = f2b((x[i] - m) * inv * g[cc] + b[cc]);
    }
    *(u16x4*)&o[base] = ov;
}

// ---------------- classifier head ----------------
__global__ __launch_bounds__(256) void classifier(
    const unsigned short* __restrict__ xin,
    const float* __restrict__ Wc1, const float* __restrict__ bc1,
    const float* __restrict__ Wc2, const float* __restrict__ bc2,
    const float* __restrict__ Wc3, const float* __restrict__ bc3,
    float* __restrict__ out)
{
    __shared__ float w1[256][9];
    __shared__ float w2[64], b2s[8], w3[16], b3s[2], b1s[8];
    int t = threadIdx.x;
    #pragma unroll
    for (int i = 0; i < 8; i++) {
        int idx = t + i * 256;
        w1[idx >> 3][idx & 7] = Wc1[idx];
    }
    if (t < 64) w2[t] = Wc2[t];
    if (t < 16) w3[t] = Wc3[t];
    if (t < 8) { b2s[t] = bc2[t]; b1s[t] = bc1[t]; }
    if (t < 2) b3s[t] = bc3[t];
    __syncthreads();
    int g = t >> 3, m = t & 7;
    size_t row = (size_t)blockIdx.x * 32 + g;
    float z[8] = {0.f,0.f,0.f,0.f,0.f,0.f,0.f,0.f};
    const unsigned short* xr = xin + row * 256 + m * 32;
    #pragma unroll
    for (int cidx = 0; cidx < 4; cidx++) {
        u16x8 xv = *(const u16x8*)&xr[cidx * 8];
        #pragma unroll
        for (int e = 0; e < 8; e++) {
            float xf = b2f(xv[e]);
            int ei = m * 32 + cidx * 8 + e;
            #pragma unroll
            for (int j = 0; j < 8; j++) z[j] = fmaf(xf, w1[ei][j], z[j]);
        }
    }
    #pragma unroll
    for (int d = 1; d < 8; d <<= 1)
        #pragma unroll
        for (int j = 0; j < 8; j++) z[j] += __shfl_xor(z[j], d);
    float z1[8], z2[8];
    #pragma unroll
    for (int j = 0; j < 8; j++) z1[j] = tanhf(z[j] + b1s[j]);
    #pragma unroll
    for (int j2 = 0; j2 < 8; j2++) {
        float sacc = b2s[j2];
        #pragma unroll
        for (int j = 0; j < 8; j++) sacc = fmaf(z1[j], w2[j * 8 + j2], sacc);
        z2[j2] = tanhf(sacc);
    }
    if (m < 2) {
        float sacc = b3s[m];
        #pragma unroll
        for (int j = 0; j < 8; j++) sacc = fmaf(z2[j], w3[j * 2 + m], sacc);
        out[row * 2 + m] = 1.f / (1.f + __expf(-sacc));
    }
}

extern "C" void kernel_launch(void* const* d_in, const int* in_sizes, int n_in,
                              void* d_out, int out_size, void* d_ws, size_t ws_size,
                              hipStream_t stream) {
    const float* x        = (const float*)d_in[0];
    const float* q        = (const float*)d_in[1];
    const int*   positions= (const int*)d_in[2];
    const float* pos_emb  = (const float*)d_in[3];
    const float* Wq       = (const float*)d_in[4];
    const float* Wk       = (const float*)d_in[5];
    const float* Wv       = (const float*)d_in[6];
    const float* Wo       = (const float*)d_in[7];
    const float* bo       = (const float*)d_in[8];
    const float* g1       = (const float*)d_in[9];
    const float* b1       = (const float*)d_in[10];
    const float* g2       = (const float*)d_in[11];
    const float* b2       = (const float*)d_in[12];
    const float* Wf1      = (const float*)d_in[13];
    const float* bf1      = (const float*)d_in[14];
    const float* Wf2      = (const float*)d_in[15];
    const float* bf2      = (const float*)d_in[16];
    const float* Wc1      = (const float*)d_in[17];
    const float* bc1      = (const float*)d_in[18];
    const float* Wc2      = (const float*)d_in[19];
    const float* bc2      = (const float*)d_in[20];
    const float* Wc3      = (const float*)d_in[21];
    const float* bc3      = (const float*)d_in[22];
    float* out = (float*)d_out;

    const int R = 512 * 90;          // 46080 token rows
    char* ws = (char*)d_ws;
    size_t off = 0;
    auto alloc = [&](size_t bytes) -> void* {
        void* p = ws + off;
        off += (bytes + 255) & ~(size_t)255;
        return p;
    };
    unsigned short* cur = (unsigned short*)alloc((size_t)R * 256 * 2);
    unsigned short* qb  = (unsigned short*)alloc((size_t)R * 256 * 2);
    unsigned short* qho = (unsigned short*)alloc((size_t)R * 256 * 2);  // attn-out -> h
    unsigned short* ka  = (unsigned short*)alloc((size_t)R * 256 * 2);  // wo-out
    unsigned short* vf  = (unsigned short*)alloc((size_t)R * 256 * 2);  // ffn2-out
    unsigned short* f1  = (unsigned short*)alloc((size_t)R * 1024 * 2);
    unsigned short* WoT = (unsigned short*)alloc((size_t)3 * 256 * 256 * 2);
    unsigned short* W1T = (unsigned short*)alloc((size_t)3 * 1024 * 256 * 2);
    unsigned short* W2T = (unsigned short*)alloc((size_t)3 * 256 * 1024 * 2);
    unsigned short* WTqkv = (unsigned short*)alloc((size_t)3 * 3 * 1024 * 2);

    for (int l = 0; l < 3; l++) {
        transpose_to_bf16<<<dim3(8, 8),  256, 0, stream>>>(Wo  + (size_t)l*256*256,  WoT + (size_t)l*256*256,  256, 256);
        transpose_to_bf16<<<dim3(8, 32), 256, 0, stream>>>(Wf1 + (size_t)l*256*1024, W1T + (size_t)l*1024*256, 256, 1024);
        transpose_to_bf16<<<dim3(32, 8), 256, 0, stream>>>(Wf2 + (size_t)l*1024*256, W2T + (size_t)l*256*1024, 1024, 256);
    }
    prep_wT<<<9, 256, 0, stream>>>(Wq, Wk, Wv, WTqkv);
    add_posemb<<<R, 256, 0, stream>>>(x, positions, pos_emb, cur);
    to_bf16_kernel<<<2048, 256, 0, stream>>>(q, qb, R * 256);

    for (int l = 0; l < 3; l++) {
        attn_kernel<<<512 * 8, 384, 0, stream>>>(cur, qb, WTqkv + (size_t)l * 3 * 1024, qho);
        gemm_bf16<0><<<dim3(R / 128, 2), 256, 0, stream>>>(qho, WoT + (size_t)l*256*256, bo + l*256, ka, R, 256, 256);
        ln_res<<<R / 4, 256, 0, stream>>>(ka, qb, g1 + l*256, b1 + l*256, qho);
        gemm_bf16<1><<<dim3(R / 128, 8), 256, 0, stream>>>(qho, W1T + (size_t)l*1024*256, bf1 + l*1024, f1, R, 1024, 256);
        gemm_bf16<0><<<dim3(R / 128, 2), 256, 0, stream>>>(f1, W2T + (size_t)l*256*1024, bf2 + l*256, vf, R, 256, 1024);
        ln_res<<<R / 4, 256, 0, stream>>>(vf, qho, g2 + l*256, b2 + l*256, cur);
    }
    classifier<<<R / 32, 256, 0, stream>>>(cur, Wc1, bc1, Wc2, bc2, Wc3, bc3, out);
}